// Round 6
// baseline (347.321 us; speedup 1.0000x reference)
//
#include <hip/hip_runtime.h>
#include <hip/hip_bf16.h>

#define NNODES 25000
#define NEDGES 400000
#define DIM 128
#define NGRAPHS 512
#define DOUT 10
#define NPAD 32768        // padded node count for scan (1024 threads * 32)
#define AGG_NB (NNODES / 8)   // 3125 blocks per feature-half

typedef short bf16x8 __attribute__((ext_vector_type(8)));
typedef float f32x4 __attribute__((ext_vector_type(4)));

__device__ inline float bfu_lo(unsigned int u) {
  union { unsigned int i; float f; } v; v.i = u << 16; return v.f;
}
__device__ inline float bfu_hi(unsigned int u) {
  union { unsigned int i; float f; } v; v.i = u & 0xffff0000u; return v.f;
}
__device__ inline unsigned short f2bf(float f) {
  union { float f; unsigned int i; } v; v.f = f;
  unsigned int r = v.i + 0x7fff + ((v.i >> 16) & 1);
  return (unsigned short)(r >> 16);
}

// ---------------- fused prep: deg histogram + x->bf16 + weight transpose ----------------

__global__ __launch_bounds__(256) void k_prep(const int* __restrict__ dst,
                                              int* __restrict__ deg,
                                              const float* __restrict__ x,
                                              unsigned short* __restrict__ h0,
                                              const float* __restrict__ W1,
                                              const float* __restrict__ W2,
                                              unsigned short* __restrict__ W1T,
                                              unsigned short* __restrict__ W2T) {
  int b = blockIdx.x;
  if (b < 1563) {
    int i = b * 256 + threadIdx.x;
    if (i < NEDGES) atomicAdd(&deg[dst[i]], 1);
  } else if (b < 3126) {
    int i = (b - 1563) * 256 + threadIdx.x;
    if (i * 8 < NNODES * DIM) {
      const float4* x4 = (const float4*)x;
      float4 a = x4[i * 2], c = x4[i * 2 + 1];
      uint4 p;
      p.x = ((unsigned int)f2bf(a.y) << 16) | f2bf(a.x);
      p.y = ((unsigned int)f2bf(a.w) << 16) | f2bf(a.z);
      p.z = ((unsigned int)f2bf(c.y) << 16) | f2bf(c.x);
      p.w = ((unsigned int)f2bf(c.w) << 16) | f2bf(c.z);
      ((uint4*)h0)[i] = p;
    }
  } else {
    int wb = b - 3126;
    int l = wb >> 1;
    const float* in = ((wb & 1) ? W2 : W1) + (size_t)l * DIM * DIM;
    unsigned short* out = ((wb & 1) ? W2T : W1T) + (size_t)l * DIM * DIM;
    for (int idx = threadIdx.x; idx < DIM * DIM; idx += 256) {
      int c = idx >> 7, k = idx & 127;
      out[idx] = f2bf(in[k * DIM + c]);
    }
  }
}

// ---------------- scan ----------------

__global__ __launch_bounds__(1024) void k_scan(const int* __restrict__ deg,
                                               int* __restrict__ offs,
                                               int* __restrict__ cursor) {
  __shared__ int tsum[1024];
  int t = threadIdx.x;
  const int4* d4 = (const int4*)(deg + t * 32);
  int4 v[8];
#pragma unroll
  for (int j = 0; j < 8; ++j) v[j] = d4[j];
  int s = 0;
#pragma unroll
  for (int j = 0; j < 8; ++j) s += v[j].x + v[j].y + v[j].z + v[j].w;
  tsum[t] = s;
  __syncthreads();
  for (int off = 1; off < 1024; off <<= 1) {
    int u = (t >= off) ? tsum[t - off] : 0;
    __syncthreads();
    tsum[t] += u;
    __syncthreads();
  }
  int run = (t == 0) ? 0 : tsum[t - 1];
  int4* o4 = (int4*)(offs + t * 32);
  int4* c4 = (int4*)(cursor + t * 32);
#pragma unroll
  for (int j = 0; j < 8; ++j) {
    int4 w;
    w.x = run; run += v[j].x;
    w.y = run; run += v[j].y;
    w.z = run; run += v[j].z;
    w.w = run; run += v[j].w;
    o4[j] = w; c4[j] = w;
  }
}

__global__ __launch_bounds__(256) void k_scatter(const int* __restrict__ src,
                                                 const int* __restrict__ dst,
                                                 int* __restrict__ cursor,
                                                 int* __restrict__ csr) {
  int i = blockIdx.x * 256 + threadIdx.x;
  if (i < NEDGES) {
    int p = atomicAdd(&cursor[dst[i]], 1);
    csr[p] = src[i];
  }
}

// ---------------- GIN aggregation (templated REPS for measurement) ----------------

template <int REPS>
__global__ __launch_bounds__(256) void k_agg(const unsigned short* __restrict__ h,
                                             const int* __restrict__ offs,
                                             const int* __restrict__ csr,
                                             const float* __restrict__ epsp, int layer,
                                             unsigned short* __restrict__ agg) {
  int blk = blockIdx.x;
  int half = (blk >= AGG_NB) ? 1 : 0;
  int nb = blk - half * AGG_NB;
  int node = nb * 8 + (threadIdx.x >> 5);
  int lane = threadIdx.x & 31;
  int base = half * 32 + lane;
  const unsigned int* hw = (const unsigned int*)h;
  float eps1 = 1.0f + epsp[layer];
  int s = offs[node], e = offs[node + 1];
  for (int rep = 0; rep < REPS; ++rep) {
    unsigned int hv = hw[(size_t)node * 64 + base];
    float a0 = eps1 * bfu_lo(hv), a1 = eps1 * bfu_hi(hv);
    float b0 = 0.f, b1 = 0.f, c0 = 0.f, c1 = 0.f;
    float d0 = 0.f, d1 = 0.f, g0 = 0.f, g1 = 0.f;
    int j = s;
    for (; j + 7 < e; j += 8) {
      int s0 = csr[j + 0], s1 = csr[j + 1], s2 = csr[j + 2], s3 = csr[j + 3];
      int s4 = csr[j + 4], s5 = csr[j + 5], s6 = csr[j + 6], s7 = csr[j + 7];
      unsigned int v0 = hw[(size_t)s0 * 64 + base];
      unsigned int v1 = hw[(size_t)s1 * 64 + base];
      unsigned int v2 = hw[(size_t)s2 * 64 + base];
      unsigned int v3 = hw[(size_t)s3 * 64 + base];
      unsigned int v4 = hw[(size_t)s4 * 64 + base];
      unsigned int v5 = hw[(size_t)s5 * 64 + base];
      unsigned int v6 = hw[(size_t)s6 * 64 + base];
      unsigned int v7 = hw[(size_t)s7 * 64 + base];
      a0 += bfu_lo(v0); a1 += bfu_hi(v0);
      b0 += bfu_lo(v1); b1 += bfu_hi(v1);
      c0 += bfu_lo(v2); c1 += bfu_hi(v2);
      d0 += bfu_lo(v3); d1 += bfu_hi(v3);
      g0 += bfu_lo(v4); g1 += bfu_hi(v4);
      a0 += bfu_lo(v5); a1 += bfu_hi(v5);
      b0 += bfu_lo(v6); b1 += bfu_hi(v6);
      c0 += bfu_lo(v7); c1 += bfu_hi(v7);
    }
    for (; j + 1 < e; j += 2) {
      int s0 = csr[j], s1 = csr[j + 1];
      unsigned int v0 = hw[(size_t)s0 * 64 + base];
      unsigned int v1 = hw[(size_t)s1 * 64 + base];
      a0 += bfu_lo(v0); a1 += bfu_hi(v0);
      b0 += bfu_lo(v1); b1 += bfu_hi(v1);
    }
    if (j < e) {
      unsigned int v = hw[(size_t)csr[j] * 64 + base];
      a0 += bfu_lo(v); a1 += bfu_hi(v);
    }
    a0 += b0 + c0 + d0 + g0;
    a1 += b1 + c1 + d1 + g1;
    ((unsigned int*)agg)[(size_t)node * 64 + base] =
        ((unsigned int)f2bf(a1) << 16) | f2bf(a0);
    asm volatile("" ::: "memory");
  }
}

// ---------------- MLP via MFMA bf16 (templated REPS for measurement) ----------------

#define MROWS 32

template <int REPS>
__global__ __launch_bounds__(256) void k_mlp(const unsigned short* __restrict__ agg,
                                             const unsigned short* __restrict__ W1T,
                                             const unsigned short* __restrict__ W2T,
                                             const float* __restrict__ b1,
                                             const float* __restrict__ gamma,
                                             const float* __restrict__ beta,
                                             const float* __restrict__ rmean,
                                             const float* __restrict__ rvar,
                                             const float* __restrict__ b2,
                                             unsigned short* __restrict__ hout) {
  __shared__ __align__(16) char smem[MROWS * 256];   // 8KB
  int t = threadIdx.x;
  int lane = t & 63;
  int wv = t >> 6;
  int r0 = blockIdx.x * MROWS;
  int cl = lane & 15;
  int kg = lane >> 4;

  for (int rep = 0; rep < REPS; ++rep) {
    {
      const uint4* ag4 = (const uint4*)(agg + (size_t)r0 * DIM);
#pragma unroll
      for (int it = 0; it < 2; ++it) {
        int u = t + it * 256;
        int row = u >> 4, un = u & 15;
        uint4 v = make_uint4(0u, 0u, 0u, 0u);
        if (r0 + row < NNODES) v = ag4[u];
        *(uint4*)(smem + row * 256 + ((un * 16) ^ ((row & 7) << 4))) = v;
      }
    }

    bf16x8 b1f[2][4], b2f[2][4];
#pragma unroll
    for (int ct = 0; ct < 2; ++ct) {
      int col = wv * 32 + ct * 16 + cl;
      const char* p1 = (const char*)(W1T + (size_t)col * DIM);
      const char* p2 = (const char*)(W2T + (size_t)col * DIM);
#pragma unroll
      for (int kk = 0; kk < 4; ++kk) {
        b1f[ct][kk] = *(const bf16x8*)(p1 + kk * 64 + kg * 16);
        b2f[ct][kk] = *(const bf16x8*)(p2 + kk * 64 + kg * 16);
      }
    }
    float s1c[2], o1c[2], b2c[2];
#pragma unroll
    for (int ct = 0; ct < 2; ++ct) {
      int col = wv * 32 + ct * 16 + cl;
      float sc = gamma[col] * rsqrtf(rvar[col] + 1e-5f);
      s1c[ct] = sc;
      o1c[ct] = (b1[col] - rmean[col]) * sc + beta[col];
      b2c[ct] = b2[col];
    }
    __syncthreads();

    f32x4 zero = {0.f, 0.f, 0.f, 0.f};
    f32x4 acc[2][2] = {{zero, zero}, {zero, zero}};
#pragma unroll
    for (int kk = 0; kk < 4; ++kk) {
#pragma unroll
      for (int rt = 0; rt < 2; ++rt) {
        int row = rt * 16 + cl;
        int un = kk * 4 + kg;
        bf16x8 a = *(const bf16x8*)(smem + row * 256 + ((un * 16) ^ ((row & 7) << 4)));
        acc[rt][0] = __builtin_amdgcn_mfma_f32_16x16x32_bf16(a, b1f[0][kk], acc[rt][0], 0, 0, 0);
        acc[rt][1] = __builtin_amdgcn_mfma_f32_16x16x32_bf16(a, b1f[1][kk], acc[rt][1], 0, 0, 0);
      }
    }
    __syncthreads();

#pragma unroll
    for (int rt = 0; rt < 2; ++rt)
#pragma unroll
      for (int ct = 0; ct < 2; ++ct) {
        int col = wv * 32 + ct * 16 + cl;
#pragma unroll
        for (int j = 0; j < 4; ++j) {
          int row = rt * 16 + kg * 4 + j;
          float z = fmaxf(acc[rt][ct][j] * s1c[ct] + o1c[ct], 0.f);
          *(unsigned short*)(smem + row * 256 + ((col * 2) ^ ((row & 7) << 4))) = f2bf(z);
        }
      }
    __syncthreads();

    f32x4 acc2[2][2] = {{zero, zero}, {zero, zero}};
#pragma unroll
    for (int kk = 0; kk < 4; ++kk) {
#pragma unroll
      for (int rt = 0; rt < 2; ++rt) {
        int row = rt * 16 + cl;
        int un = kk * 4 + kg;
        bf16x8 a = *(const bf16x8*)(smem + row * 256 + ((un * 16) ^ ((row & 7) << 4)));
        acc2[rt][0] = __builtin_amdgcn_mfma_f32_16x16x32_bf16(a, b2f[0][kk], acc2[rt][0], 0, 0, 0);
        acc2[rt][1] = __builtin_amdgcn_mfma_f32_16x16x32_bf16(a, b2f[1][kk], acc2[rt][1], 0, 0, 0);
      }
    }
    __syncthreads();

#pragma unroll
    for (int rt = 0; rt < 2; ++rt)
#pragma unroll
      for (int ct = 0; ct < 2; ++ct) {
        int col = wv * 32 + ct * 16 + cl;
#pragma unroll
        for (int j = 0; j < 4; ++j) {
          int row = rt * 16 + kg * 4 + j;
          float hv = fmaxf(acc2[rt][ct][j] + b2c[ct], 0.f);
          *(unsigned short*)(smem + row * 256 + ((col * 2) ^ ((row & 7) << 4))) = f2bf(hv);
        }
      }
    __syncthreads();

    {
      uint4* ho4 = (uint4*)(hout + (size_t)r0 * DIM);
#pragma unroll
      for (int it = 0; it < 2; ++it) {
        int u = t + it * 256;
        int row = u >> 4, un = u & 15;
        if (r0 + row < NNODES) {
          uint4 v = *(const uint4*)(smem + row * 256 + ((un * 16) ^ ((row & 7) << 4)));
          ho4[u] = v;
        }
      }
    }
    __syncthreads();
    asm volatile("" ::: "memory");
  }
}

// ---------------- mean-pool + final linear ----------------

__device__ inline int lower_bound_i(const int* a, int n, int key) {
  int lo = 0, hi = n;
  while (lo < hi) {
    int m = (lo + hi) >> 1;
    if (a[m] < key) lo = m + 1; else hi = m;
  }
  return lo;
}

__global__ __launch_bounds__(256) void k_pool(const unsigned short* __restrict__ h,
                                              const int* __restrict__ batch,
                                              const float* __restrict__ Wout,
                                              const float* __restrict__ bout,
                                              float* __restrict__ out) {
  int g = blockIdx.x;
  int t = threadIdx.x;
  int cg = t & 31;
  int st = t >> 5;
  int lo = lower_bound_i(batch, NNODES, g);
  int hi = lower_bound_i(batch, NNODES, g + 1);
  const uint2* h2 = (const uint2*)h;
  float a0 = 0.f, a1 = 0.f, a2 = 0.f, a3 = 0.f;
  for (int i = lo + st; i < hi; i += 8) {
    uint2 v = h2[(size_t)i * 32 + cg];
    a0 += bfu_lo(v.x); a1 += bfu_hi(v.x); a2 += bfu_lo(v.y); a3 += bfu_hi(v.y);
  }
  __shared__ float red[8][DIM];
  __shared__ float pooled[DIM];
  red[st][cg * 4 + 0] = a0; red[st][cg * 4 + 1] = a1;
  red[st][cg * 4 + 2] = a2; red[st][cg * 4 + 3] = a3;
  __syncthreads();
  if (t < DIM) {
    float s = 0.f;
#pragma unroll
    for (int k = 0; k < 8; ++k) s += red[k][t];
    float cnt = (hi > lo) ? (float)(hi - lo) : 1.0f;
    pooled[t] = s / cnt;
  }
  __syncthreads();
  if (t < DOUT) {
    float acc = bout[t];
#pragma unroll 8
    for (int k = 0; k < DIM; ++k) acc = fmaf(pooled[k], Wout[k * DOUT + t], acc);
    out[g * DOUT + t] = acc;
  }
}

// ---------------- launch ----------------

extern "C" void kernel_launch(void* const* d_in, const int* in_sizes, int n_in,
                              void* d_out, int out_size, void* d_ws, size_t ws_size,
                              hipStream_t stream) {
  const float* x     = (const float*)d_in[0];
  const int*   ei    = (const int*)d_in[1];
  const int*   batch = (const int*)d_in[2];
  const float* W1    = (const float*)d_in[3];
  const float* b1    = (const float*)d_in[4];
  const float* gamma = (const float*)d_in[5];
  const float* beta  = (const float*)d_in[6];
  const float* rmean = (const float*)d_in[7];
  const float* rvar  = (const float*)d_in[8];
  const float* W2    = (const float*)d_in[9];
  const float* b2    = (const float*)d_in[10];
  const float* eps   = (const float*)d_in[11];
  const float* Wout  = (const float*)d_in[12];
  const float* bout  = (const float*)d_in[13];
  float* out = (float*)d_out;

  const int* src = ei;
  const int* dst = ei + NEDGES;

  char* ws = (char*)d_ws;
  size_t o = 0;
  auto alloc = [&](size_t bytes) -> void* {
    o = (o + 255) & ~(size_t)255;
    void* p = ws + o;
    o += bytes;
    return p;
  };
  int* deg    = (int*)alloc(NPAD * sizeof(int));
  int* offs   = (int*)alloc((NPAD + 8) * sizeof(int));
  int* cursor = (int*)alloc(NPAD * sizeof(int));
  int* csr    = (int*)alloc(NEDGES * sizeof(int));
  unsigned short* h0  = (unsigned short*)alloc((size_t)NNODES * DIM * 2);
  unsigned short* agg = (unsigned short*)alloc((size_t)NNODES * DIM * 2);
  unsigned short* hA  = (unsigned short*)alloc((size_t)NNODES * DIM * 2);
  unsigned short* hB  = (unsigned short*)alloc((size_t)NNODES * DIM * 2);
  unsigned short* W1T = (unsigned short*)alloc(3 * DIM * DIM * 2);
  unsigned short* W2T = (unsigned short*)alloc(3 * DIM * DIM * 2);

  hipMemsetAsync(deg, 0, NPAD * sizeof(int), stream);
  k_prep<<<3132, 256, 0, stream>>>(dst, deg, x, h0, W1, W2, W1T, W2T);
  k_scan<<<1, 1024, 0, stream>>>(deg, offs, cursor);
  k_scatter<<<(NEDGES + 255) / 256, 256, 0, stream>>>(src, dst, cursor, csr);

  const unsigned short* hin = h0;
  unsigned short* houts[3] = {hA, hB, hA};
  for (int l = 0; l < 3; ++l) {
    if (l == 0) {
      k_agg<8><<<AGG_NB * 2, 256, 0, stream>>>(hin, offs, csr, eps, l, agg);
      k_mlp<8><<<(NNODES + MROWS - 1) / MROWS, 256, 0, stream>>>(
          agg, W1T + (size_t)l * DIM * DIM, W2T + (size_t)l * DIM * DIM,
          b1 + l * DIM, gamma + l * DIM, beta + l * DIM, rmean + l * DIM,
          rvar + l * DIM, b2 + l * DIM, houts[l]);
    } else {
      k_agg<1><<<AGG_NB * 2, 256, 0, stream>>>(hin, offs, csr, eps, l, agg);
      k_mlp<1><<<(NNODES + MROWS - 1) / MROWS, 256, 0, stream>>>(
          agg, W1T + (size_t)l * DIM * DIM, W2T + (size_t)l * DIM * DIM,
          b1 + l * DIM, gamma + l * DIM, beta + l * DIM, rmean + l * DIM,
          rvar + l * DIM, b2 + l * DIM, houts[l]);
    }
    hin = houts[l];
  }
  k_pool<<<NGRAPHS, 256, 0, stream>>>(hin, batch, Wout, bout, out);
}

// Round 7
// 247.492 us; speedup vs baseline: 1.4034x; 1.4034x over previous
//
#include <hip/hip_runtime.h>
#include <hip/hip_bf16.h>

#define NNODES 25000
#define NEDGES 400000
#define DIM 128
#define NGRAPHS 512
#define DOUT 10
#define NPAD 32768        // padded node count for scan (1024 threads * 32)

typedef short bf16x8 __attribute__((ext_vector_type(8)));
typedef float f32x4 __attribute__((ext_vector_type(4)));

__device__ inline float bfu_lo(unsigned int u) {
  union { unsigned int i; float f; } v; v.i = u << 16; return v.f;
}
__device__ inline float bfu_hi(unsigned int u) {
  union { unsigned int i; float f; } v; v.i = u & 0xffff0000u; return v.f;
}
__device__ inline unsigned short f2bf(float f) {
  union { float f; unsigned int i; } v; v.f = f;
  unsigned int r = v.i + 0x7fff + ((v.i >> 16) & 1);
  return (unsigned short)(r >> 16);
}

// ---------------- fused prep: deg histogram + x->bf16 + weight transpose ----------------

__global__ __launch_bounds__(256) void k_prep(const int* __restrict__ dst,
                                              int* __restrict__ deg,
                                              const float* __restrict__ x,
                                              unsigned short* __restrict__ h0,
                                              const float* __restrict__ W1,
                                              const float* __restrict__ W2,
                                              unsigned short* __restrict__ W1T,
                                              unsigned short* __restrict__ W2T) {
  int b = blockIdx.x;
  if (b < 1563) {
    int i = b * 256 + threadIdx.x;
    if (i < NEDGES) atomicAdd(&deg[dst[i]], 1);
  } else if (b < 3126) {
    int i = (b - 1563) * 256 + threadIdx.x;
    if (i * 8 < NNODES * DIM) {
      const float4* x4 = (const float4*)x;
      float4 a = x4[i * 2], c = x4[i * 2 + 1];
      uint4 p;
      p.x = ((unsigned int)f2bf(a.y) << 16) | f2bf(a.x);
      p.y = ((unsigned int)f2bf(a.w) << 16) | f2bf(a.z);
      p.z = ((unsigned int)f2bf(c.y) << 16) | f2bf(c.x);
      p.w = ((unsigned int)f2bf(c.w) << 16) | f2bf(c.z);
      ((uint4*)h0)[i] = p;
    }
  } else {
    int wb = b - 3126;
    int l = wb >> 1;
    const float* in = ((wb & 1) ? W2 : W1) + (size_t)l * DIM * DIM;
    unsigned short* out = ((wb & 1) ? W2T : W1T) + (size_t)l * DIM * DIM;
    for (int idx = threadIdx.x; idx < DIM * DIM; idx += 256) {
      int c = idx >> 7, k = idx & 127;
      out[idx] = f2bf(in[k * DIM + c]);
    }
  }
}

// ---------------- scan ----------------

__global__ __launch_bounds__(1024) void k_scan(const int* __restrict__ deg,
                                               int* __restrict__ offs,
                                               int* __restrict__ cursor) {
  __shared__ int tsum[1024];
  int t = threadIdx.x;
  const int4* d4 = (const int4*)(deg + t * 32);
  int4 v[8];
#pragma unroll
  for (int j = 0; j < 8; ++j) v[j] = d4[j];
  int s = 0;
#pragma unroll
  for (int j = 0; j < 8; ++j) s += v[j].x + v[j].y + v[j].z + v[j].w;
  tsum[t] = s;
  __syncthreads();
  for (int off = 1; off < 1024; off <<= 1) {
    int u = (t >= off) ? tsum[t - off] : 0;
    __syncthreads();
    tsum[t] += u;
    __syncthreads();
  }
  int run = (t == 0) ? 0 : tsum[t - 1];
  int4* o4 = (int4*)(offs + t * 32);
  int4* c4 = (int4*)(cursor + t * 32);
#pragma unroll
  for (int j = 0; j < 8; ++j) {
    int4 w;
    w.x = run; run += v[j].x;
    w.y = run; run += v[j].y;
    w.z = run; run += v[j].z;
    w.w = run; run += v[j].w;
    o4[j] = w; c4[j] = w;
  }
}

__global__ __launch_bounds__(256) void k_scatter(const int* __restrict__ src,
                                                 const int* __restrict__ dst,
                                                 int* __restrict__ cursor,
                                                 int* __restrict__ csr) {
  int i = blockIdx.x * 256 + threadIdx.x;
  if (i < NEDGES) {
    int p = atomicAdd(&cursor[dst[i]], 1);
    csr[p] = src[i];
  }
}

// ---------------- GIN aggregation: one wave per node, scalarized CSR ----------------
// 64 lanes x 4B = one full 256B bf16 row per load instruction.
// offs/csr are wave-uniform -> SGPR via readfirstlane -> s_load for indices,
// saddr-form global_load with 32-bit voffset for rows (h is 6.4MB).

__global__ __launch_bounds__(256) void k_agg(const unsigned short* __restrict__ h,
                                             const int* __restrict__ offs,
                                             const int* __restrict__ csr,
                                             const float* __restrict__ epsp, int layer,
                                             unsigned short* __restrict__ agg) {
  int lane = threadIdx.x & 63;
  int node = blockIdx.x * 4 + (threadIdx.x >> 6);   // grid*4 == NNODES exactly
  const char* hb = (const char*)h;
  unsigned laneB = (unsigned)lane * 4u;
  float eps1 = 1.0f + epsp[layer];
  int s = __builtin_amdgcn_readfirstlane(offs[node]);
  int e = __builtin_amdgcn_readfirstlane(offs[node + 1]);

  unsigned int hv = *(const unsigned int*)(hb + (((unsigned)node << 8) + laneB));
  float a0 = eps1 * bfu_lo(hv), a1 = eps1 * bfu_hi(hv);
  float b0 = 0.f, b1 = 0.f, c0 = 0.f, c1 = 0.f, d0 = 0.f, d1 = 0.f, g0 = 0.f, g1 = 0.f;

  int j = s;
  for (; j + 7 < e; j += 8) {
    unsigned o0 = (unsigned)__builtin_amdgcn_readfirstlane(csr[j + 0]) << 8;
    unsigned o1 = (unsigned)__builtin_amdgcn_readfirstlane(csr[j + 1]) << 8;
    unsigned o2 = (unsigned)__builtin_amdgcn_readfirstlane(csr[j + 2]) << 8;
    unsigned o3 = (unsigned)__builtin_amdgcn_readfirstlane(csr[j + 3]) << 8;
    unsigned o4 = (unsigned)__builtin_amdgcn_readfirstlane(csr[j + 4]) << 8;
    unsigned o5 = (unsigned)__builtin_amdgcn_readfirstlane(csr[j + 5]) << 8;
    unsigned o6 = (unsigned)__builtin_amdgcn_readfirstlane(csr[j + 6]) << 8;
    unsigned o7 = (unsigned)__builtin_amdgcn_readfirstlane(csr[j + 7]) << 8;
    unsigned int v0 = *(const unsigned int*)(hb + (o0 + laneB));
    unsigned int v1 = *(const unsigned int*)(hb + (o1 + laneB));
    unsigned int v2 = *(const unsigned int*)(hb + (o2 + laneB));
    unsigned int v3 = *(const unsigned int*)(hb + (o3 + laneB));
    unsigned int v4 = *(const unsigned int*)(hb + (o4 + laneB));
    unsigned int v5 = *(const unsigned int*)(hb + (o5 + laneB));
    unsigned int v6 = *(const unsigned int*)(hb + (o6 + laneB));
    unsigned int v7 = *(const unsigned int*)(hb + (o7 + laneB));
    a0 += bfu_lo(v0); a1 += bfu_hi(v0);
    b0 += bfu_lo(v1); b1 += bfu_hi(v1);
    c0 += bfu_lo(v2); c1 += bfu_hi(v2);
    d0 += bfu_lo(v3); d1 += bfu_hi(v3);
    g0 += bfu_lo(v4); g1 += bfu_hi(v4);
    a0 += bfu_lo(v5); a1 += bfu_hi(v5);
    b0 += bfu_lo(v6); b1 += bfu_hi(v6);
    c0 += bfu_lo(v7); c1 += bfu_hi(v7);
  }
  for (; j < e; ++j) {
    unsigned o = (unsigned)__builtin_amdgcn_readfirstlane(csr[j]) << 8;
    unsigned int v = *(const unsigned int*)(hb + (o + laneB));
    a0 += bfu_lo(v); a1 += bfu_hi(v);
  }
  a0 += b0 + c0 + d0 + g0;
  a1 += b1 + c1 + d1 + g1;
  ((unsigned int*)agg)[((unsigned)node << 6) + lane] =
      ((unsigned int)f2bf(a1) << 16) | f2bf(a0);
}

// ---------------- MLP via MFMA bf16 (R3-proven) ----------------

#define MROWS 32

__global__ __launch_bounds__(256) void k_mlp(const unsigned short* __restrict__ agg,
                                             const unsigned short* __restrict__ W1T,
                                             const unsigned short* __restrict__ W2T,
                                             const float* __restrict__ b1,
                                             const float* __restrict__ gamma,
                                             const float* __restrict__ beta,
                                             const float* __restrict__ rmean,
                                             const float* __restrict__ rvar,
                                             const float* __restrict__ b2,
                                             unsigned short* __restrict__ hout) {
  __shared__ __align__(16) char smem[MROWS * 256];   // 8KB
  int t = threadIdx.x;
  int lane = t & 63;
  int wv = t >> 6;
  int r0 = blockIdx.x * MROWS;
  int cl = lane & 15;
  int kg = lane >> 4;

  {
    const uint4* ag4 = (const uint4*)(agg + (size_t)r0 * DIM);
#pragma unroll
    for (int it = 0; it < 2; ++it) {
      int u = t + it * 256;
      int row = u >> 4, un = u & 15;
      uint4 v = make_uint4(0u, 0u, 0u, 0u);
      if (r0 + row < NNODES) v = ag4[u];
      *(uint4*)(smem + row * 256 + ((un * 16) ^ ((row & 7) << 4))) = v;
    }
  }

  bf16x8 b1f[2][4], b2f[2][4];
#pragma unroll
  for (int ct = 0; ct < 2; ++ct) {
    int col = wv * 32 + ct * 16 + cl;
    const char* p1 = (const char*)(W1T + (size_t)col * DIM);
    const char* p2 = (const char*)(W2T + (size_t)col * DIM);
#pragma unroll
    for (int kk = 0; kk < 4; ++kk) {
      b1f[ct][kk] = *(const bf16x8*)(p1 + kk * 64 + kg * 16);
      b2f[ct][kk] = *(const bf16x8*)(p2 + kk * 64 + kg * 16);
    }
  }
  float s1c[2], o1c[2], b2c[2];
#pragma unroll
  for (int ct = 0; ct < 2; ++ct) {
    int col = wv * 32 + ct * 16 + cl;
    float sc = gamma[col] * rsqrtf(rvar[col] + 1e-5f);
    s1c[ct] = sc;
    o1c[ct] = (b1[col] - rmean[col]) * sc + beta[col];
    b2c[ct] = b2[col];
  }
  __syncthreads();

  f32x4 zero = {0.f, 0.f, 0.f, 0.f};
  f32x4 acc[2][2] = {{zero, zero}, {zero, zero}};
#pragma unroll
  for (int kk = 0; kk < 4; ++kk) {
#pragma unroll
    for (int rt = 0; rt < 2; ++rt) {
      int row = rt * 16 + cl;
      int un = kk * 4 + kg;
      bf16x8 a = *(const bf16x8*)(smem + row * 256 + ((un * 16) ^ ((row & 7) << 4)));
      acc[rt][0] = __builtin_amdgcn_mfma_f32_16x16x32_bf16(a, b1f[0][kk], acc[rt][0], 0, 0, 0);
      acc[rt][1] = __builtin_amdgcn_mfma_f32_16x16x32_bf16(a, b1f[1][kk], acc[rt][1], 0, 0, 0);
    }
  }
  __syncthreads();

#pragma unroll
  for (int rt = 0; rt < 2; ++rt)
#pragma unroll
    for (int ct = 0; ct < 2; ++ct) {
      int col = wv * 32 + ct * 16 + cl;
#pragma unroll
      for (int j = 0; j < 4; ++j) {
        int row = rt * 16 + kg * 4 + j;
        float z = fmaxf(acc[rt][ct][j] * s1c[ct] + o1c[ct], 0.f);
        *(unsigned short*)(smem + row * 256 + ((col * 2) ^ ((row & 7) << 4))) = f2bf(z);
      }
    }
  __syncthreads();

  f32x4 acc2[2][2] = {{zero, zero}, {zero, zero}};
#pragma unroll
  for (int kk = 0; kk < 4; ++kk) {
#pragma unroll
    for (int rt = 0; rt < 2; ++rt) {
      int row = rt * 16 + cl;
      int un = kk * 4 + kg;
      bf16x8 a = *(const bf16x8*)(smem + row * 256 + ((un * 16) ^ ((row & 7) << 4)));
      acc2[rt][0] = __builtin_amdgcn_mfma_f32_16x16x32_bf16(a, b2f[0][kk], acc2[rt][0], 0, 0, 0);
      acc2[rt][1] = __builtin_amdgcn_mfma_f32_16x16x32_bf16(a, b2f[1][kk], acc2[rt][1], 0, 0, 0);
    }
  }
  __syncthreads();

#pragma unroll
  for (int rt = 0; rt < 2; ++rt)
#pragma unroll
    for (int ct = 0; ct < 2; ++ct) {
      int col = wv * 32 + ct * 16 + cl;
#pragma unroll
      for (int j = 0; j < 4; ++j) {
        int row = rt * 16 + kg * 4 + j;
        float hv = fmaxf(acc2[rt][ct][j] + b2c[ct], 0.f);
        *(unsigned short*)(smem + row * 256 + ((col * 2) ^ ((row & 7) << 4))) = f2bf(hv);
      }
    }
  __syncthreads();

  {
    uint4* ho4 = (uint4*)(hout + (size_t)r0 * DIM);
#pragma unroll
    for (int it = 0; it < 2; ++it) {
      int u = t + it * 256;
      int row = u >> 4, un = u & 15;
      if (r0 + row < NNODES) {
        uint4 v = *(const uint4*)(smem + row * 256 + ((un * 16) ^ ((row & 7) << 4)));
        ho4[u] = v;
      }
    }
  }
}

// ---------------- mean-pool + final linear ----------------

__device__ inline int lower_bound_i(const int* a, int n, int key) {
  int lo = 0, hi = n;
  while (lo < hi) {
    int m = (lo + hi) >> 1;
    if (a[m] < key) lo = m + 1; else hi = m;
  }
  return lo;
}

__global__ __launch_bounds__(256) void k_pool(const unsigned short* __restrict__ h,
                                              const int* __restrict__ batch,
                                              const float* __restrict__ Wout,
                                              const float* __restrict__ bout,
                                              float* __restrict__ out) {
  int g = blockIdx.x;
  int t = threadIdx.x;
  int cg = t & 31;
  int st = t >> 5;
  int lo = lower_bound_i(batch, NNODES, g);
  int hi = lower_bound_i(batch, NNODES, g + 1);
  const uint2* h2 = (const uint2*)h;
  float a0 = 0.f, a1 = 0.f, a2 = 0.f, a3 = 0.f;
  for (int i = lo + st; i < hi; i += 8) {
    uint2 v = h2[(size_t)i * 32 + cg];
    a0 += bfu_lo(v.x); a1 += bfu_hi(v.x); a2 += bfu_lo(v.y); a3 += bfu_hi(v.y);
  }
  __shared__ float red[8][DIM];
  __shared__ float pooled[DIM];
  red[st][cg * 4 + 0] = a0; red[st][cg * 4 + 1] = a1;
  red[st][cg * 4 + 2] = a2; red[st][cg * 4 + 3] = a3;
  __syncthreads();
  if (t < DIM) {
    float s = 0.f;
#pragma unroll
    for (int k = 0; k < 8; ++k) s += red[k][t];
    float cnt = (hi > lo) ? (float)(hi - lo) : 1.0f;
    pooled[t] = s / cnt;
  }
  __syncthreads();
  if (t < DOUT) {
    float acc = bout[t];
#pragma unroll 8
    for (int k = 0; k < DIM; ++k) acc = fmaf(pooled[k], Wout[k * DOUT + t], acc);
    out[g * DOUT + t] = acc;
  }
}

// ---------------- launch ----------------

extern "C" void kernel_launch(void* const* d_in, const int* in_sizes, int n_in,
                              void* d_out, int out_size, void* d_ws, size_t ws_size,
                              hipStream_t stream) {
  const float* x     = (const float*)d_in[0];
  const int*   ei    = (const int*)d_in[1];
  const int*   batch = (const int*)d_in[2];
  const float* W1    = (const float*)d_in[3];
  const float* b1    = (const float*)d_in[4];
  const float* gamma = (const float*)d_in[5];
  const float* beta  = (const float*)d_in[6];
  const float* rmean = (const float*)d_in[7];
  const float* rvar  = (const float*)d_in[8];
  const float* W2    = (const float*)d_in[9];
  const float* b2    = (const float*)d_in[10];
  const float* eps   = (const float*)d_in[11];
  const float* Wout  = (const float*)d_in[12];
  const float* bout  = (const float*)d_in[13];
  float* out = (float*)d_out;

  const int* src = ei;
  const int* dst = ei + NEDGES;

  char* ws = (char*)d_ws;
  size_t o = 0;
  auto alloc = [&](size_t bytes) -> void* {
    o = (o + 255) & ~(size_t)255;
    void* p = ws + o;
    o += bytes;
    return p;
  };
  int* deg    = (int*)alloc(NPAD * sizeof(int));
  int* offs   = (int*)alloc((NPAD + 8) * sizeof(int));
  int* cursor = (int*)alloc(NPAD * sizeof(int));
  int* csr    = (int*)alloc(NEDGES * sizeof(int));
  unsigned short* h0  = (unsigned short*)alloc((size_t)NNODES * DIM * 2);
  unsigned short* agg = (unsigned short*)alloc((size_t)NNODES * DIM * 2);
  unsigned short* hA  = (unsigned short*)alloc((size_t)NNODES * DIM * 2);
  unsigned short* hB  = (unsigned short*)alloc((size_t)NNODES * DIM * 2);
  unsigned short* W1T = (unsigned short*)alloc(3 * DIM * DIM * 2);
  unsigned short* W2T = (unsigned short*)alloc(3 * DIM * DIM * 2);

  hipMemsetAsync(deg, 0, NPAD * sizeof(int), stream);
  k_prep<<<3132, 256, 0, stream>>>(dst, deg, x, h0, W1, W2, W1T, W2T);
  k_scan<<<1, 1024, 0, stream>>>(deg, offs, cursor);
  k_scatter<<<(NEDGES + 255) / 256, 256, 0, stream>>>(src, dst, cursor, csr);

  const unsigned short* hin = h0;
  unsigned short* houts[3] = {hA, hB, hA};
  for (int l = 0; l < 3; ++l) {
    k_agg<<<NNODES / 4, 256, 0, stream>>>(hin, offs, csr, eps, l, agg);
    k_mlp<<<(NNODES + MROWS - 1) / MROWS, 256, 0, stream>>>(
        agg, W1T + (size_t)l * DIM * DIM, W2T + (size_t)l * DIM * DIM,
        b1 + l * DIM, gamma + l * DIM, beta + l * DIM, rmean + l * DIM,
        rvar + l * DIM, b2 + l * DIM, houts[l]);
    hin = houts[l];
  }
  k_pool<<<NGRAPHS, 256, 0, stream>>>(hin, batch, Wout, bout, out);
}